// Round 13
// baseline (186.277 us; speedup 1.0000x reference)
//
#include <hip/hip_runtime.h>
#if __has_include(<hip/hip_fp8.h>)
#include <hip/hip_fp8.h>
#endif

// ---------------------------------------------------------------------------
// MHABlock: cvt (+l_tot zero, sqrt-softmax-scale in Wq AND Wk) -> QKV GEMM
// (bf16, BK=64, global_load_lds) -> K transpose->fp8 / V transpose->bf16
// (+vals zero) -> split-K(3) flash attention:
//   S^T = K(fp8,LDS) x Q(fp8,regs)  [mfma 16x16x32 fp8]
//   P = exp2(S^T) converted IN REGISTERS to the A-operand of
//   mfma_f32_16x16x16bf16_1k (C/D row=quad*4+r == A k=quad*4+j) -> PV needs
//   NO LDS round-trip, no mid barrier. V bf16 in LDS as B-operand.
//   All LDS fragment reads tile 512B exactly -> conflict-free by construction.
// -> deferred normalize + residual + LayerNorm.
// ---------------------------------------------------------------------------

typedef __bf16 bf16x8 __attribute__((ext_vector_type(8)));
typedef __bf16 bf16x4 __attribute__((ext_vector_type(4)));
typedef float  f32x4  __attribute__((ext_vector_type(4)));
typedef unsigned short u16x4 __attribute__((ext_vector_type(4)));
typedef short          s16x4 __attribute__((ext_vector_type(4)));
typedef long           la64  __attribute__((may_alias));

#define N_TOK   4096
#define D_MODEL 640
#define DK      64
#define HSLAB   (N_TOK * DK)
// sqrt(log2(e)/64): folded into BOTH Wq and Wk -> logits arrive base-2 scaled
#define SQS 0.15014030f

#if __has_builtin(__builtin_amdgcn_exp2f)
#define EXP2(x) __builtin_amdgcn_exp2f(x)
#else
#define EXP2(x) exp2f(x)
#endif

__device__ __forceinline__ void stage16(const void* g, void* lds_uniform) {
    __builtin_amdgcn_global_load_lds(
        (const __attribute__((address_space(1))) unsigned int*)g,
        (__attribute__((address_space(3))) unsigned int*)lds_uniform, 16, 0, 0);
}

__device__ __forceinline__ u16x4 cvt4(f32x4 v) {
    return __builtin_bit_cast(u16x4, __builtin_convertvector(v, bf16x4));
}

__device__ __forceinline__ unsigned int pk_fp8(f32x4 v) {
#if __has_builtin(__builtin_amdgcn_cvt_pk_fp8_f32)
    int r = 0;
    r = __builtin_amdgcn_cvt_pk_fp8_f32(v[0], v[1], r, false);
    r = __builtin_amdgcn_cvt_pk_fp8_f32(v[2], v[3], r, true);
    return (unsigned int)r;
#else
    union { unsigned char b[4]; unsigned int u; } x;
    x.b[0] = __hip_fp8_e4m3(v[0]).__x;
    x.b[1] = __hip_fp8_e4m3(v[1]).__x;
    x.b[2] = __hip_fp8_e4m3(v[2]).__x;
    x.b[3] = __hip_fp8_e4m3(v[3]).__x;
    return x.u;
#endif
}

// K=16 bf16 MFMA, 4x i16 operands (gfx90a+ "_1k" spelling)
__device__ __forceinline__ f32x4 mfma16bf(s16x4 a, s16x4 b, f32x4 c) {
    return __builtin_amdgcn_mfma_f32_16x16x16bf16_1k(a, b, c, 0, 0, 0);
}

// ---------- fused fp32 -> bf16 (x, Wq*s, Wk*s, Wv) + l_tot zeroing ---------
__global__ __launch_bounds__(256) void cvt_all(const float* __restrict__ x,
                                               const float* __restrict__ w0,
                                               const float* __restrict__ w1,
                                               const float* __restrict__ w2,
                                               unsigned short* __restrict__ xb,
                                               unsigned short* __restrict__ d0,
                                               unsigned short* __restrict__ d1,
                                               unsigned short* __restrict__ d2,
                                               f32x4* __restrict__ ltot4) {
    int i = blockIdx.x * 256 + threadIdx.x;
    if (i >= 962560) { ltot4[i - 962560] = (f32x4){0.f, 0.f, 0.f, 0.f}; return; }
    const float* s; unsigned short* d; int off; float scl = 1.0f;
    if (i < 655360) { s = x; d = xb; off = i; }
    else {
        int j = i - 655360;
        int w = j / 102400; off = j - w * 102400;
        s = (w == 0) ? w0 : (w == 1) ? w1 : w2;
        d = (w == 0) ? d0 : (w == 1) ? d1 : d2;
        if (w < 2) scl = SQS;
    }
    f32x4 v = ((const f32x4*)s)[off];
    v[0] *= scl; v[1] *= scl; v[2] *= scl; v[3] *= scl;
    ((u16x4*)d)[off] = cvt4(v);
}

// ------------------------ QKV NT-GEMM: C = x @ W^T -------------------------
__global__ __launch_bounds__(256, 2) void gemm_qkv(
    const unsigned short* __restrict__ xb,
    const unsigned short* __restrict__ wq,
    const unsigned short* __restrict__ wk,
    const unsigned short* __restrict__ wv,
    unsigned short* __restrict__ Qo,
    unsigned short* __restrict__ Ko,
    unsigned short* __restrict__ Vo) {
    const int mode = blockIdx.z;
    const unsigned short* W = (mode == 0) ? wq : (mode == 1) ? wk : wv;
    unsigned short*       C = (mode == 0) ? Qo : (mode == 1) ? Ko : Vo;
    const int m0 = blockIdx.y * 128;
    const int n0 = blockIdx.x * 128;

    __shared__ unsigned short As[8192];
    __shared__ unsigned short Bs[8192];

    const int tid  = threadIdx.x;
    const int lane = tid & 63;
    const int wave = tid >> 6;
    const int quad = lane >> 4, l16 = lane & 15;
    const int wm = (wave >> 1) * 64, wn = (wave & 1) * 64;
    const int swz = l16 & 7;

    f32x4 acc[4][4] = {};

    int prow[4], pcol[4], lbase[4];
    for (int j = 0; j < 4; j++) {
        int p = j * 256 + tid;
        prow[j] = p >> 3;
        pcol[j] = ((p & 7) ^ (prow[j] & 7)) * 8;
        lbase[j] = (j * 256 + wave * 64) * 8;
    }

    for (int kt = 0; kt < D_MODEL; kt += 64) {
        __syncthreads();
        for (int j = 0; j < 4; j++) {
            stage16(&xb[(size_t)(m0 + prow[j]) * D_MODEL + kt + pcol[j]], As + lbase[j]);
            stage16(&W [(size_t)(n0 + prow[j]) * D_MODEL + kt + pcol[j]], Bs + lbase[j]);
        }
        __syncthreads();

        for (int s = 0; s < 2; s++) {
            bf16x8 af[4], bfr[4];
            for (int mi = 0; mi < 4; mi++) {
                int row = wm + mi * 16 + l16;
                af[mi] = *(const bf16x8*)&As[row * 64 + (((s << 2) + quad) ^ swz) * 8];
            }
            for (int ni = 0; ni < 4; ni++) {
                int row = wn + ni * 16 + l16;
                bfr[ni] = *(const bf16x8*)&Bs[row * 64 + (((s << 2) + quad) ^ swz) * 8];
            }
            for (int mi = 0; mi < 4; mi++)
                for (int ni = 0; ni < 4; ni++)
                    acc[mi][ni] = __builtin_amdgcn_mfma_f32_16x16x32_bf16(af[mi], bfr[ni], acc[mi][ni], 0, 0, 0);
        }
    }

    for (int mi = 0; mi < 4; mi++)
        for (int ni = 0; ni < 4; ni++) {
            u16x4 cv = cvt4(acc[mi][ni]);
            for (int r = 0; r < 4; r++) {
                int row = m0 + wm + mi * 16 + quad * 4 + r;
                int col = n0 + wn + ni * 16 + l16;
                C[(size_t)row * D_MODEL + col] = cv[r];
            }
        }
}

// -- per-head transpose: K -> fp8 K'[key][dk]; V -> bf16 V'[dk][key]; zero --
__global__ __launch_bounds__(256) void transpose_kv(
    const unsigned short* __restrict__ Kn, unsigned char* __restrict__ Kp8,
    const unsigned short* __restrict__ Vn, unsigned short* __restrict__ Vpb) {
    const int z = blockIdx.z;
    const int t = threadIdx.x;

    __shared__ unsigned short T[64][66];
    const unsigned short* src;
    int Cc, r0, c0;
    if (z < 10) { src = Kn; Cc = 4096; r0 = 0; c0 = blockIdx.x * 64; }
    else        { src = Vn; Cc = 64;   r0 = blockIdx.x * 64; c0 = 0; }
    const size_t hb = (size_t)(z % 10) * HSLAB;
    const int rr = t >> 3, c8 = (t & 7) * 8;

    for (int hf = 0; hf < 2; hf++) {
        int r = rr + hf * 32;
        bf16x8 v = *(const bf16x8*)&src[hb + (size_t)(r0 + r) * Cc + c0 + c8];
        for (int j = 0; j < 8; j++) T[r][c8 + j] = ((unsigned short*)&v)[j];
    }
    __syncthreads();
    // zero the consumed source tile (Kn+Vn exactly cover the fp32 vals buf)
    const bf16x8 zz = {};
    for (int hf = 0; hf < 2; hf++) {
        int r = rr + hf * 32;
        *(bf16x8*)&((unsigned short*)src)[hb + (size_t)(r0 + r) * Cc + c0 + c8] = zz;
    }
    if (z < 10) {
        for (int hf = 0; hf < 2; hf++) {
            int oc = rr + hf * 32;   // key
            f32x4 lo, hi;
            for (int j = 0; j < 4; j++) {
                lo[j] = __builtin_bit_cast(float, (unsigned int)T[c8 + j][oc] << 16);
                hi[j] = __builtin_bit_cast(float, (unsigned int)T[c8 + 4 + j][oc] << 16);
            }
            uint2 ov; ov.x = pk_fp8(lo); ov.y = pk_fp8(hi);
            *(uint2*)&Kp8[hb + (size_t)(c0 + oc) * 64 + r0 + c8] = ov;
        }
    } else {
        for (int hf = 0; hf < 2; hf++) {
            int oc = rr + hf * 32;   // dk
            unsigned short v[8];
            for (int j = 0; j < 8; j++) v[j] = T[c8 + j][oc];
            *(bf16x8*)&Vpb[hb + (size_t)oc * 4096 + r0 + c8] = *(bf16x8*)v;
        }
    }
}

// ------------------------------- attention ---------------------------------
// grid (320, 3): x = head*32 + qtile(128 rows), y = kpart (11/11/10 tiles of
// 128 keys). 4 waves x 32 q. LDS: K fp8 8KB + V bf16 16KB = 24KB.
// K LDS addr(key,ci,half) = (key>>4)*1024+(ci>>1)*512+(key&15)*32+(ci&1)*16+half*8
// V LDS addr(dk,key)      = (dk>>4)*4096+(key>>4)*512+(dk&15)*32+((key>>2)&3)*8
// Both fragment reads tile 512B exactly -> conflict-free.
__global__ __launch_bounds__(256, 5) void attn(
    const unsigned short* __restrict__ Qn,   // [h][q][dk] bf16
    const unsigned char*  __restrict__ Kp8,  // [h][key][dk] fp8
    const unsigned short* __restrict__ Vpb,  // [h][dk][key] bf16
    float* __restrict__ vals,                // pre-zeroed (transpose_kv)
    float* __restrict__ l_tot) {             // pre-zeroed (cvt_all)
    const int h  = blockIdx.x >> 5;
    const int qt = blockIdx.x & 31;
    const int ntile = (blockIdx.y == 2) ? 10 : 11;
    const int tile0 = blockIdx.y * 11;
    const int lane = threadIdx.x & 63;
    const int wave = threadIdx.x >> 6;
    const int quad = lane >> 4, l16 = lane & 15;
    const size_t hoff = (size_t)h * HSLAB;

    __shared__ unsigned char Kt[8192];
    __shared__ unsigned char Vt[32768 - 8192];   // 16KB used (pad keeps 24KB block)

    // Q: load bf16, convert to fp8 B-operand fragments (once per kernel)
    const int qbase = qt * 128 + wave * 32;
    long qd[2][2];
    for (int g = 0; g < 2; g++)
        for (int s = 0; s < 2; s++) {
            bf16x8 qv = *(const bf16x8*)&Qn[hoff + (size_t)(qbase + g * 16 + l16) * DK + s * 32 + quad * 8];
            f32x4 lo = {(float)qv[0], (float)qv[1], (float)qv[2], (float)qv[3]};
            f32x4 hi = {(float)qv[4], (float)qv[5], (float)qv[6], (float)qv[7]};
            uint2 t2; t2.x = pk_fp8(lo); t2.y = pk_fp8(hi);
            qd[g][s] = __builtin_bit_cast(long, t2);
        }

    f32x4 o[2][4] = {};
    f32x4 ol[2] = {};
    const s16x4 ONES4 = (s16x4)(short)0x3F80;    // bf16 1.0 x4

    // staging lane maps
    const int l = lane;
    const int kKey0 = wave * 32 + ((l >> 1) & 15);           // instr wave*2
    const int kCi   = (((l >> 5) & 1) << 1) | (l & 1);
    const int vDk   = wave * 16 + ((l >> 1) & 15);
    const int vKc   = (((l >> 5) & 1) << 1) | (l & 1);       // + j*4

    // fragment-read bases (conflict-free by construction)
    const int kfb = l16 * 32 + (quad >> 1) * 16 + (quad & 1) * 8;
    const int vfb = l16 * 32 + quad * 8;

    for (int t = 0; t < ntile; t++) {
        const int keyb = (tile0 + t) << 7;
        __syncthreads();
        stage16(Kp8 + hoff + (size_t)(keyb + kKey0) * 64 + kCi * 16, Kt + wave * 2048);
        stage16(Kp8 + hoff + (size_t)(keyb + kKey0 + 16) * 64 + kCi * 16, Kt + wave * 2048 + 1024);
        for (int j = 0; j < 4; j++)
            stage16(Vpb + hoff + (size_t)vDk * 4096 + keyb + (j * 4 + vKc) * 8,
                    Vt + wave * 4096 + j * 1024);
        __syncthreads();

        for (int ni = 0; ni < 8; ni++) {
            const unsigned char* kp = Kt + ni * 1024 + kfb;
            long a0 = *(const la64*)(kp);
            long a1 = *(const la64*)(kp + 512);
            s16x4 vb[4];
            for (int nd = 0; nd < 4; nd++)
                vb[nd] = __builtin_bit_cast(s16x4,
                    *(const la64*)(Vt + nd * 4096 + ni * 512 + vfb));
            for (int g = 0; g < 2; g++) {
                f32x4 s = {};
                s = __builtin_amdgcn_mfma_f32_16x16x32_fp8_fp8(a0, qd[g][0], s, 0, 0, 0);
                s = __builtin_amdgcn_mfma_f32_16x16x32_fp8_fp8(a1, qd[g][1], s, 0, 0, 0);
                // lane: S^T[key=ni*16+quad*4+r][q=g*16+l16] == PV A-frag layout
                f32x4 pv;
                for (int r = 0; r < 4; r++) pv[r] = EXP2(s[r]);
                s16x4 A = __builtin_bit_cast(s16x4, cvt4(pv));
                ol[g] = mfma16bf(A, ONES4, ol[g]);
                for (int nd = 0; nd < 4; nd++)
                    o[g][nd] = mfma16bf(A, vb[nd], o[g][nd]);
            }
        }
    }

    if (l16 == 0)
        for (int g = 0; g < 2; g++)
            for (int r = 0; r < 4; r++)
                atomicAdd(&l_tot[(h << 12) + qbase + g * 16 + quad * 4 + r], ol[g][r]);

    for (int g = 0; g < 2; g++)
        for (int nd = 0; nd < 4; nd++)
            for (int r = 0; r < 4; r++) {
                int q = qbase + g * 16 + quad * 4 + r;
                atomicAdd(&vals[hoff + (size_t)q * DK + nd * 16 + l16], o[g][nd][r]);
            }
}

// ----------------- deferred normalize + residual + LayerNorm ---------------
__global__ __launch_bounds__(256) void ln_kernel(
    const float* __restrict__ vals, const float* __restrict__ l_tot,
    const float* __restrict__ x,
    const float* __restrict__ gamma, const float* __restrict__ beta,
    float* __restrict__ out) {
    const int wave = threadIdx.x >> 6, lane = threadIdx.x & 63;
    const int row  = blockIdx.x * 4 + wave;
    const float* v  = vals + (size_t)row * D_MODEL;
    const float* xr = x    + (size_t)row * D_MODEL;

    float t[10];
    float s = 0.f;
    for (int i = 0; i < 10; i++) {
        float linv = 1.0f / l_tot[row * 10 + i];
        t[i] = v[lane + i * 64] * linv + xr[lane + i * 64];
        s += t[i];
    }
    for (int off = 32; off; off >>= 1) s += __shfl_xor(s, off, 64);
    float mean = s * (1.0f / 640.0f);
    float s2 = 0.f;
    for (int i = 0; i < 10; i++) { float d = t[i] - mean; s2 += d * d; }
    for (int off = 32; off; off >>= 1) s2 += __shfl_xor(s2, off, 64);
    float inv = rsqrtf(s2 * (1.0f / 640.0f) + 1e-5f);

    float* orow = out + (size_t)row * D_MODEL;
    for (int i = 0; i < 10; i++) {
        int c = lane + i * 64;
        orow[c] = (t[i] - mean) * inv * gamma[c] + beta[c];
    }
}

// ------------------------------- launcher ----------------------------------
extern "C" void kernel_launch(void* const* d_in, const int* in_sizes, int n_in,
                              void* d_out, int out_size, void* d_ws, size_t ws_size,
                              hipStream_t stream) {
    const float* x     = (const float*)d_in[0];
    const float* Wq    = (const float*)d_in[1];
    const float* Wk    = (const float*)d_in[2];
    const float* Wv    = (const float*)d_in[3];
    const float* gamma = (const float*)d_in[4];
    const float* beta  = (const float*)d_in[5];
    float* out = (float*)d_out;

    char* ws = (char*)d_ws;
    unsigned short* xb  = (unsigned short*)(ws);               // 5,242,880 B
    unsigned char*  Kp8 = (unsigned char*)(ws);                // overlays xb (dead after gemm)
    unsigned short* wqb = (unsigned short*)(ws + 5242880);
    unsigned short* wkb = (unsigned short*)(ws + 6062080);
    unsigned short* wvb = (unsigned short*)(ws + 6881280);
    unsigned short* Qn  = (unsigned short*)(ws + 7700480);     // bf16 Q natural
    unsigned short* Vpb = (unsigned short*)(ws + 12943360);    // bf16 V' [h][dk][key]
    unsigned short* Kn  = (unsigned short*)(ws + 23429120);    // aliases vals
    unsigned short* Vn  = (unsigned short*)(ws + 28672000);    //  (exactly)
    float*          vals  = (float*)(ws + 23429120);           // 10,485,760 B
    float*          l_tot = (float*)(ws + 33914880);           //   163,840 B

    cvt_all<<<3800, 256, 0, stream>>>(x, Wq, Wk, Wv, xb, wqb, wkb, wvb,
                                      (f32x4*)l_tot);

    gemm_qkv<<<dim3(5, 32, 3), 256, 0, stream>>>(xb, wqb, wkb, wvb, Qn, Kn, Vn);

    transpose_kv<<<dim3(64, 1, 20), 256, 0, stream>>>(Kn, Kp8, Vn, Vpb);

    attn<<<dim3(320, 3), 256, 0, stream>>>(Qn, Kp8, Vpb, vals, l_tot);
    ln_kernel<<<1024, 256, 0, stream>>>(vals, l_tot, x, gamma, beta, out);
}

// Round 14
// 154.281 us; speedup vs baseline: 1.2074x; 1.2074x over previous
//
#include <hip/hip_runtime.h>
#if __has_include(<hip/hip_fp8.h>)
#include <hip/hip_fp8.h>
#endif

// ---------------------------------------------------------------------------
// MHABlock: cvt (+l_tot zero, sqrt-softmax-scale folded into Wq AND Wk) ->
// QKV GEMM (bf16, BK=64, global_load_lds) -> fused K/V transpose + fp8
// convert (+Q->fp8, +vals zero) -> split-K(3) fp8 flash attention with
// R10-proven LDS layouts, restructured to 2 barriers/tile:
//   ping-pong K staging (1 tile ahead) + V staged under the S-phase;
//   the mid-P barrier's implicit vmcnt(0) drain guarantees V readiness.
// -> deferred normalize + residual + LayerNorm.
// ---------------------------------------------------------------------------

typedef __bf16 bf16x8 __attribute__((ext_vector_type(8)));
typedef __bf16 bf16x4 __attribute__((ext_vector_type(4)));
typedef float  f32x4  __attribute__((ext_vector_type(4)));
typedef unsigned short u16x4 __attribute__((ext_vector_type(4)));
typedef unsigned int   u32x4 __attribute__((ext_vector_type(4)));
typedef long           la64  __attribute__((may_alias));
typedef unsigned int   ua32  __attribute__((may_alias));

#define N_TOK   4096
#define D_MODEL 640
#define DK      64
#define HSLAB   (N_TOK * DK)
// sqrt(log2(e)/64): folded into BOTH Wq and Wk -> logits arrive base-2 scaled
#define SQS 0.15014030f

#if __has_builtin(__builtin_amdgcn_exp2f)
#define EXP2(x) __builtin_amdgcn_exp2f(x)
#else
#define EXP2(x) exp2f(x)
#endif

__device__ __forceinline__ void stage16(const void* g, void* lds_uniform) {
    __builtin_amdgcn_global_load_lds(
        (const __attribute__((address_space(1))) unsigned int*)g,
        (__attribute__((address_space(3))) unsigned int*)lds_uniform, 16, 0, 0);
}

__device__ __forceinline__ u16x4 cvt4(f32x4 v) {
    return __builtin_bit_cast(u16x4, __builtin_convertvector(v, bf16x4));
}

__device__ __forceinline__ unsigned int pk_fp8(f32x4 v) {
#if __has_builtin(__builtin_amdgcn_cvt_pk_fp8_f32)
    int r = 0;
    r = __builtin_amdgcn_cvt_pk_fp8_f32(v[0], v[1], r, false);
    r = __builtin_amdgcn_cvt_pk_fp8_f32(v[2], v[3], r, true);
    return (unsigned int)r;
#else
    union { unsigned char b[4]; unsigned int u; } x;
    x.b[0] = __hip_fp8_e4m3(v[0]).__x;
    x.b[1] = __hip_fp8_e4m3(v[1]).__x;
    x.b[2] = __hip_fp8_e4m3(v[2]).__x;
    x.b[3] = __hip_fp8_e4m3(v[3]).__x;
    return x.u;
#endif
}

// ---------- fused fp32 -> bf16 (x, Wq*s, Wk*s, Wv) + l_tot zeroing ---------
__global__ __launch_bounds__(256) void cvt_all(const float* __restrict__ x,
                                               const float* __restrict__ w0,
                                               const float* __restrict__ w1,
                                               const float* __restrict__ w2,
                                               unsigned short* __restrict__ xb,
                                               unsigned short* __restrict__ d0,
                                               unsigned short* __restrict__ d1,
                                               unsigned short* __restrict__ d2,
                                               f32x4* __restrict__ ltot4) {
    int i = blockIdx.x * 256 + threadIdx.x;
    if (i >= 962560) { ltot4[i - 962560] = (f32x4){0.f, 0.f, 0.f, 0.f}; return; }
    const float* s; unsigned short* d; int off; float scl = 1.0f;
    if (i < 655360) { s = x; d = xb; off = i; }
    else {
        int j = i - 655360;
        int w = j / 102400; off = j - w * 102400;
        s = (w == 0) ? w0 : (w == 1) ? w1 : w2;
        d = (w == 0) ? d0 : (w == 1) ? d1 : d2;
        if (w < 2) scl = SQS;   // Wq, Wk carry sqrt of softmax scale
    }
    f32x4 v = ((const f32x4*)s)[off];
    v[0] *= scl; v[1] *= scl; v[2] *= scl; v[3] *= scl;
    ((u16x4*)d)[off] = cvt4(v);
}

// ------------------------ QKV NT-GEMM: C = x @ W^T -------------------------
// M=4096, N=640, K=640. 128x128 tile, BK=64, 4 waves each 64x64.
__global__ __launch_bounds__(256, 2) void gemm_qkv(
    const unsigned short* __restrict__ xb,
    const unsigned short* __restrict__ wq,
    const unsigned short* __restrict__ wk,
    const unsigned short* __restrict__ wv,
    unsigned short* __restrict__ Qo,
    unsigned short* __restrict__ Ko,
    unsigned short* __restrict__ Vo) {
    const int mode = blockIdx.z;
    const unsigned short* W = (mode == 0) ? wq : (mode == 1) ? wk : wv;
    unsigned short*       C = (mode == 0) ? Qo : (mode == 1) ? Ko : Vo;
    const int m0 = blockIdx.y * 128;
    const int n0 = blockIdx.x * 128;

    __shared__ unsigned short As[8192];   // 128 rows x 64
    __shared__ unsigned short Bs[8192];

    const int tid  = threadIdx.x;
    const int lane = tid & 63;
    const int wave = tid >> 6;
    const int quad = lane >> 4, l16 = lane & 15;
    const int wm = (wave >> 1) * 64, wn = (wave & 1) * 64;
    const int swz = l16 & 7;

    f32x4 acc[4][4] = {};

    int prow[4], pcol[4], lbase[4];
    for (int j = 0; j < 4; j++) {
        int p = j * 256 + tid;
        prow[j] = p >> 3;
        pcol[j] = ((p & 7) ^ (prow[j] & 7)) * 8;
        lbase[j] = (j * 256 + wave * 64) * 8;
    }

    for (int kt = 0; kt < D_MODEL; kt += 64) {
        __syncthreads();
        for (int j = 0; j < 4; j++) {
            stage16(&xb[(size_t)(m0 + prow[j]) * D_MODEL + kt + pcol[j]], As + lbase[j]);
            stage16(&W [(size_t)(n0 + prow[j]) * D_MODEL + kt + pcol[j]], Bs + lbase[j]);
        }
        __syncthreads();

        for (int s = 0; s < 2; s++) {
            bf16x8 af[4], bfr[4];
            for (int mi = 0; mi < 4; mi++) {
                int row = wm + mi * 16 + l16;
                af[mi] = *(const bf16x8*)&As[row * 64 + (((s << 2) + quad) ^ swz) * 8];
            }
            for (int ni = 0; ni < 4; ni++) {
                int row = wn + ni * 16 + l16;
                bfr[ni] = *(const bf16x8*)&Bs[row * 64 + (((s << 2) + quad) ^ swz) * 8];
            }
            for (int mi = 0; mi < 4; mi++)
                for (int ni = 0; ni < 4; ni++)
                    acc[mi][ni] = __builtin_amdgcn_mfma_f32_16x16x32_bf16(af[mi], bfr[ni], acc[mi][ni], 0, 0, 0);
        }
    }

    for (int mi = 0; mi < 4; mi++)
        for (int ni = 0; ni < 4; ni++) {
            u16x4 cv = cvt4(acc[mi][ni]);
            for (int r = 0; r < 4; r++) {
                int row = m0 + wm + mi * 16 + quad * 4 + r;
                int col = n0 + wn + ni * 16 + l16;
                C[(size_t)row * D_MODEL + col] = cv[r];
            }
        }
}

// ------ fused per-head transpose -> fp8 (K',V') + Q->fp8 + vals zero -------
__global__ __launch_bounds__(256) void transpose_kv(
    const unsigned short* __restrict__ Kn, unsigned char* __restrict__ Kp8,
    const unsigned short* __restrict__ Vn, unsigned char* __restrict__ Vp8,
    const unsigned short* __restrict__ Qn, unsigned char* __restrict__ Qf8) {
    const int z = blockIdx.z;
    const int t = threadIdx.x;

    if (z >= 20) {   // Q convert: head slab, flat
        const size_t base = (size_t)(z - 20) * HSLAB + blockIdx.x * 4096 + t * 16;
        bf16x8 v0 = *(const bf16x8*)&Qn[base];
        bf16x8 v1 = *(const bf16x8*)&Qn[base + 8];
        f32x4 a = {(float)v0[0], (float)v0[1], (float)v0[2], (float)v0[3]};
        f32x4 b = {(float)v0[4], (float)v0[5], (float)v0[6], (float)v0[7]};
        f32x4 c = {(float)v1[0], (float)v1[1], (float)v1[2], (float)v1[3]};
        f32x4 d = {(float)v1[4], (float)v1[5], (float)v1[6], (float)v1[7]};
        u32x4 o = {pk_fp8(a), pk_fp8(b), pk_fp8(c), pk_fp8(d)};
        *(u32x4*)&Qf8[base] = o;
        return;
    }

    __shared__ unsigned short T[64][66];
    const unsigned short* src; unsigned char* dst;
    int R, Cc, r0, c0;
    if (z < 10) { src = Kn; dst = Kp8; R = 64;   Cc = 4096; r0 = 0; c0 = blockIdx.x * 64; }
    else        { src = Vn; dst = Vp8; R = 4096; Cc = 64;   r0 = blockIdx.x * 64; c0 = 0; }
    const size_t hb = (size_t)(z % 10) * HSLAB;
    const int rr = t >> 3, c8 = (t & 7) * 8;

    for (int hf = 0; hf < 2; hf++) {
        int r = rr + hf * 32;
        bf16x8 v = *(const bf16x8*)&src[hb + (size_t)(r0 + r) * Cc + c0 + c8];
        for (int j = 0; j < 8; j++) T[r][c8 + j] = ((unsigned short*)&v)[j];
    }
    __syncthreads();
    // zero the consumed source tile (Kn+Vn exactly cover the fp32 vals buf)
    const bf16x8 zz = {};
    for (int hf = 0; hf < 2; hf++) {
        int r = rr + hf * 32;
        *(bf16x8*)&((unsigned short*)src)[hb + (size_t)(r0 + r) * Cc + c0 + c8] = zz;
    }
    for (int hf = 0; hf < 2; hf++) {
        int oc = rr + hf * 32;
        f32x4 lo, hi;
        for (int j = 0; j < 4; j++) {
            lo[j] = __builtin_bit_cast(float, (unsigned int)T[c8 + j][oc] << 16);
            hi[j] = __builtin_bit_cast(float, (unsigned int)T[c8 + 4 + j][oc] << 16);
        }
        uint2 ov; ov.x = pk_fp8(lo); ov.y = pk_fp8(hi);
        size_t dcol = (z < 10) ? ((size_t)(c0 + oc) * 64 + r0 + c8)
                               : ((size_t)oc * 4096 + r0 + c8);
        *(uint2*)&dst[hb + dcol] = ov;
    }
}

// ------------------------------- attention (fp8) ---------------------------
// grid (320, 3): x = head*32 + qtile(128 rows), y = kpart (11/11/10 tiles of
// 128 keys). 4 waves x 32 q. R10-proven layouts; 2 barriers/tile:
//   top barrier -> stage K[t+1] (ping-pong) + V[t] -> S-phase (K[t], exp2,
//   P->LDS) -> mid barrier (drains vmcnt: V[t] ready, P visible) -> PV.
// LDS: K 2x8KB + V 8KB + P 16KB = 40KB -> exactly 4 blocks/CU.
__global__ __launch_bounds__(256, 4) void attn(
    const unsigned char* __restrict__ Qf8,   // [h][q][dk] fp8
    const unsigned char* __restrict__ Kp8,   // [h][key][dk] fp8
    const unsigned char* __restrict__ Vp8,   // [h][dk][key] fp8
    float* __restrict__ vals,                // pre-zeroed (transpose_kv)
    float* __restrict__ l_tot) {             // pre-zeroed (cvt_all)
    const int h  = blockIdx.x >> 5;
    const int qt = blockIdx.x & 31;
    const int ntile = (blockIdx.y == 2) ? 10 : 11;
    const int tile0 = blockIdx.y * 11;
    const int lane = threadIdx.x & 63;
    const int wave = threadIdx.x >> 6;
    const int quad = lane >> 4, l16 = lane & 15;
    const size_t hoff = (size_t)h * HSLAB;

    __shared__ unsigned char sm[40960];
    unsigned char* const Kb0 = sm;                      // 8KB, ping
    unsigned char* const Kb1 = sm + 8192;               // 8KB, pong
    unsigned char* const Vt  = sm + 16384;              // 8KB
    unsigned char* const Pw  = sm + 24576 + wave * 4096;// 4KB/wave

    const int qbase = qt * 128 + wave * 32;
    long qd[2][2];
    for (int g = 0; g < 2; g++) {
        const unsigned char* qp = Qf8 + hoff + (size_t)(qbase + g * 16 + l16) * 64 + quad * 8;
        qd[g][0] = *(const la64*)(qp);
        qd[g][1] = *(const la64*)(qp + 32);
    }

    f32x4 o[2][4] = {};
    f32x4 ol[2] = {};
    const long ONES8 = 0x3838383838383838L;   // e4m3 1.0 x8

    // staging: LDS chunk c holds: K (key=(c>>5)*8+(c&7), ci=(c>>3)&3)
    //                             V (dk =(c>>6)*8+(c&7), cv=(c>>3)&7)
    const int cA = wave * 64 + lane, cB = cA + 256;
    const int kKeyA = ((cA >> 5) << 3) + (cA & 7), kCiA = (cA >> 3) & 3;
    const int kKeyB = ((cB >> 5) << 3) + (cB & 7), kCiB = (cB >> 3) & 3;
    const int vDkA  = ((cA >> 6) << 3) + (cA & 7), vCvA = (cA >> 3) & 7;
    const int vDkB  = ((cB >> 6) << 3) + (cB & 7), vCvB = (cB >> 3) & 7;

    // fragment-read bases (R10-proven)
    const int kfb = (l16 >> 3) * 512 + (quad >> 1) * 128 + (l16 & 7) * 16 + (quad & 1) * 8;
    const int vfb = (l16 >> 3) * 1024 + (quad >> 1) * 128 + (l16 & 7) * 16 + (quad & 1) * 8;

    // prologue: stage K tile 0 into Kb0
    {
        const int keyb = tile0 << 7;
        stage16(Kp8 + hoff + (size_t)(keyb + kKeyA) * 64 + kCiA * 16, Kb0 + wave * 1024);
        stage16(Kp8 + hoff + (size_t)(keyb + kKeyB) * 64 + kCiB * 16, Kb0 + 4096 + wave * 1024);
    }

    for (int t = 0; t < ntile; t++) {
        const int keyb = (tile0 + t) << 7;
        unsigned char* const Kcur = (t & 1) ? Kb1 : Kb0;

        // K[t] was drained by the previous mid barrier (or is drained here for
        // t=0); Vt/Pw reads of t-1 are complete; K[t+1] buffer is free.
        __syncthreads();

        if (t + 1 < ntile) {
            const int keyn = (tile0 + t + 1) << 7;
            unsigned char* const Knext = (t & 1) ? Kb0 : Kb1;
            stage16(Kp8 + hoff + (size_t)(keyn + kKeyA) * 64 + kCiA * 16, Knext + wave * 1024);
            stage16(Kp8 + hoff + (size_t)(keyn + kKeyB) * 64 + kCiB * 16, Knext + 4096 + wave * 1024);
        }
        stage16(Vp8 + hoff + (size_t)vDkA * N_TOK + keyb + vCvA * 16, Vt + wave * 1024);
        stage16(Vp8 + hoff + (size_t)vDkB * N_TOK + keyb + vCvB * 16, Vt + 4096 + wave * 1024);

        // ---- S^T: A = K rows (key), B = Q (pre-scaled); exp2 -> P fp8 ----
        for (int ni = 0; ni < 8; ni++) {
            const unsigned char* kp = Kcur + ni * 1024 + kfb;
            long a0 = *(const la64*)(kp);
            long a1 = *(const la64*)(kp + 256);
            for (int g = 0; g < 2; g++) {
                f32x4 s = {};
                s = __builtin_amdgcn_mfma_f32_16x16x32_fp8_fp8(a0, qd[g][0], s, 0, 0, 0);
                s = __builtin_amdgcn_mfma_f32_16x16x32_fp8_fp8(a1, qd[g][1], s, 0, 0, 0);
                f32x4 pv;
                for (int r = 0; r < 4; r++) pv[r] = EXP2(s[r]);
                *(ua32*)(Pw + (ni * 2 + (quad >> 1)) * 256 +
                         (g * 16 + l16) * 8 + (quad & 1) * 4) = pk_fp8(pv);
            }
        }

        // Drains vmcnt (V[t] + K[t+1] staged) and lgkmcnt (P visible).
        __syncthreads();

        // ---- O += P * V, l += P * 1 ----
        for (int ks = 0; ks < 4; ks++) {
            long vf[4];
            for (int nd = 0; nd < 4; nd++)
                vf[nd] = *(const la64*)(Vt + nd * 2048 + ks * 256 + vfb);
            for (int g = 0; g < 2; g++) {
                long pf = *(const la64*)(Pw + (ks * 4 + quad) * 256 + (g * 16 + l16) * 8);
                ol[g] = __builtin_amdgcn_mfma_f32_16x16x32_fp8_fp8(pf, ONES8, ol[g], 0, 0, 0);
                for (int nd = 0; nd < 4; nd++)
                    o[g][nd] = __builtin_amdgcn_mfma_f32_16x16x32_fp8_fp8(pf, vf[nd], o[g][nd], 0, 0, 0);
            }
        }
    }

    // l: C rows = q offset quad*4+r, cols identical -> write from l16==0
    if (l16 == 0)
        for (int g = 0; g < 2; g++)
            for (int r = 0; r < 4; r++)
                atomicAdd(&l_tot[(h << 12) + qbase + g * 16 + quad * 4 + r], ol[g][r]);

    for (int g = 0; g < 2; g++)
        for (int nd = 0; nd < 4; nd++)
            for (int r = 0; r < 4; r++) {
                int q = qbase + g * 16 + quad * 4 + r;
                atomicAdd(&vals[hoff + (size_t)q * DK + nd * 16 + l16], o[g][nd][r]);
            }
}

// ----------------- deferred normalize + residual + LayerNorm ---------------
__global__ __launch_bounds__(256) void ln_kernel(
    const float* __restrict__ vals, const float* __restrict__ l_tot,
    const float* __restrict__ x,
    const float* __restrict__ gamma, const float* __restrict__ beta,
    float* __restrict__ out) {
    const int wave = threadIdx.x >> 6, lane = threadIdx.x & 63;
    const int row  = blockIdx.x * 4 + wave;
    const float* v  = vals + (size_t)row * D_MODEL;
    const float* xr = x    + (size_t)row * D_MODEL;

    float t[10];
    float s = 0.f;
    for (int i = 0; i < 10; i++) {
        float linv = 1.0f / l_tot[row * 10 + i];
        t[i] = v[lane + i * 64] * linv + xr[lane + i * 64];
        s += t[i];
    }
    for (int off = 32; off; off >>= 1) s += __shfl_xor(s, off, 64);
    float mean = s * (1.0f / 640.0f);
    float s2 = 0.f;
    for (int i = 0; i < 10; i++) { float d = t[i] - mean; s2 += d * d; }
    for (int off = 32; off; off >>= 1) s2 += __shfl_xor(s2, off, 64);
    float inv = rsqrtf(s2 * (1.0f / 640.0f) + 1e-5f);

    float* orow = out + (size_t)row * D_MODEL;
    for (int i = 0; i < 10; i++) {
        int c = lane + i * 64;
        orow[c] = (t[i] - mean) * inv * gamma[c] + beta[c];
    }
}

// ------------------------------- launcher ----------------------------------
extern "C" void kernel_launch(void* const* d_in, const int* in_sizes, int n_in,
                              void* d_out, int out_size, void* d_ws, size_t ws_size,
                              hipStream_t stream) {
    const float* x     = (const float*)d_in[0];
    const float* Wq    = (const float*)d_in[1];
    const float* Wk    = (const float*)d_in[2];
    const float* Wv    = (const float*)d_in[3];
    const float* gamma = (const float*)d_in[4];
    const float* beta  = (const float*)d_in[5];
    float* out = (float*)d_out;

    char* ws = (char*)d_ws;
    unsigned short* xb  = (unsigned short*)(ws);               // 5,242,880 B
    unsigned char*  Qf8 = (unsigned char*)(ws);                // overlays xb (dead after gemm)
    unsigned short* wqb = (unsigned short*)(ws + 5242880);
    unsigned short* wkb = (unsigned short*)(ws + 6062080);
    unsigned short* wvb = (unsigned short*)(ws + 6881280);
    unsigned short* Qn  = (unsigned short*)(ws + 7700480);     // bf16 Q natural
    unsigned char*  Kp8 = (unsigned char*)(ws + 12943360);     // fp8 K' [h][key][dk]
    unsigned char*  Vp8 = (unsigned char*)(ws + 18186240);     // fp8 V' [h][dk][key]
    unsigned short* Kn  = (unsigned short*)(ws + 23429120);    // aliases vals
    unsigned short* Vn  = (unsigned short*)(ws + 28672000);    //  (exactly)
    float*          vals  = (float*)(ws + 23429120);           // 10,485,760 B
    float*          l_tot = (float*)(ws + 33914880);           //   163,840 B

    cvt_all<<<3800, 256, 0, stream>>>(x, Wq, Wk, Wv, xb, wqb, wkb, wvb,
                                      (f32x4*)l_tot);

    gemm_qkv<<<dim3(5, 32, 3), 256, 0, stream>>>(xb, wqb, wkb, wvb, Qn, Kn, Vn);

    transpose_kv<<<dim3(64, 1, 30), 256, 0, stream>>>(Kn, Kp8, Vn, Vp8, Qn, Qf8);

    attn<<<dim3(320, 3), 256, 0, stream>>>(Qf8, Kp8, Vp8, vals, l_tot);
    ln_kernel<<<1024, 256, 0, stream>>>(vals, l_tot, x, gamma, beta, out);
}

// Round 15
// 153.277 us; speedup vs baseline: 1.2153x; 1.0065x over previous
//
#include <hip/hip_runtime.h>
#if __has_include(<hip/hip_fp8.h>)
#include <hip/hip_fp8.h>
#endif

// ---------------------------------------------------------------------------
// MHABlock: cvt (+l_tot zero, sqrt-softmax-scale folded into Wq AND Wk) ->
// QKV GEMM (bf16, BK=64, global_load_lds, XCD-pinned m-tiles: all 15
// (n,mode) blocks of an m-tile on one XCD -> x fetched from HBM once) ->
// fused K/V transpose + fp8 convert (+Q->fp8, +vals zero) -> split-K(3) fp8
// flash attention (R14 2-barrier ping-pong) -> deferred normalize + LN.
// ---------------------------------------------------------------------------

typedef __bf16 bf16x8 __attribute__((ext_vector_type(8)));
typedef __bf16 bf16x4 __attribute__((ext_vector_type(4)));
typedef float  f32x4  __attribute__((ext_vector_type(4)));
typedef unsigned short u16x4 __attribute__((ext_vector_type(4)));
typedef unsigned int   u32x4 __attribute__((ext_vector_type(4)));
typedef long           la64  __attribute__((may_alias));
typedef unsigned int   ua32  __attribute__((may_alias));

#define N_TOK   4096
#define D_MODEL 640
#define DK      64
#define HSLAB   (N_TOK * DK)
// sqrt(log2(e)/64): folded into BOTH Wq and Wk -> logits arrive base-2 scaled
#define SQS 0.15014030f

#if __has_builtin(__builtin_amdgcn_exp2f)
#define EXP2(x) __builtin_amdgcn_exp2f(x)
#else
#define EXP2(x) exp2f(x)
#endif

__device__ __forceinline__ void stage16(const void* g, void* lds_uniform) {
    __builtin_amdgcn_global_load_lds(
        (const __attribute__((address_space(1))) unsigned int*)g,
        (__attribute__((address_space(3))) unsigned int*)lds_uniform, 16, 0, 0);
}

__device__ __forceinline__ u16x4 cvt4(f32x4 v) {
    return __builtin_bit_cast(u16x4, __builtin_convertvector(v, bf16x4));
}

__device__ __forceinline__ unsigned int pk_fp8(f32x4 v) {
#if __has_builtin(__builtin_amdgcn_cvt_pk_fp8_f32)
    int r = 0;
    r = __builtin_amdgcn_cvt_pk_fp8_f32(v[0], v[1], r, false);
    r = __builtin_amdgcn_cvt_pk_fp8_f32(v[2], v[3], r, true);
    return (unsigned int)r;
#else
    union { unsigned char b[4]; unsigned int u; } x;
    x.b[0] = __hip_fp8_e4m3(v[0]).__x;
    x.b[1] = __hip_fp8_e4m3(v[1]).__x;
    x.b[2] = __hip_fp8_e4m3(v[2]).__x;
    x.b[3] = __hip_fp8_e4m3(v[3]).__x;
    return x.u;
#endif
}

// ---------- fused fp32 -> bf16 (x, Wq*s, Wk*s, Wv) + l_tot zeroing ---------
__global__ __launch_bounds__(256) void cvt_all(const float* __restrict__ x,
                                               const float* __restrict__ w0,
                                               const float* __restrict__ w1,
                                               const float* __restrict__ w2,
                                               unsigned short* __restrict__ xb,
                                               unsigned short* __restrict__ d0,
                                               unsigned short* __restrict__ d1,
                                               unsigned short* __restrict__ d2,
                                               f32x4* __restrict__ ltot4) {
    int i = blockIdx.x * 256 + threadIdx.x;
    if (i >= 962560) { ltot4[i - 962560] = (f32x4){0.f, 0.f, 0.f, 0.f}; return; }
    const float* s; unsigned short* d; int off; float scl = 1.0f;
    if (i < 655360) { s = x; d = xb; off = i; }
    else {
        int j = i - 655360;
        int w = j / 102400; off = j - w * 102400;
        s = (w == 0) ? w0 : (w == 1) ? w1 : w2;
        d = (w == 0) ? d0 : (w == 1) ? d1 : d2;
        if (w < 2) scl = SQS;   // Wq, Wk carry sqrt of softmax scale
    }
    f32x4 v = ((const f32x4*)s)[off];
    v[0] *= scl; v[1] *= scl; v[2] *= scl; v[3] *= scl;
    ((u16x4*)d)[off] = cvt4(v);
}

// ------------------------ QKV NT-GEMM: C = x @ W^T -------------------------
// M=4096, N=640, K=640. 128x128 tile, BK=64, 4 waves each 64x64.
// Grid = 480 linear. m-tile g = b&31 -> g%8 == b%8 == XCD id: all 15
// (n,mode) blocks sharing an m-tile are pinned to one XCD, so the x m-tile
// is fetched from HBM once and served from that XCD's L2 to the rest.
__global__ __launch_bounds__(256, 2) void gemm_qkv(
    const unsigned short* __restrict__ xb,
    const unsigned short* __restrict__ wq,
    const unsigned short* __restrict__ wk,
    const unsigned short* __restrict__ wv,
    unsigned short* __restrict__ Qo,
    unsigned short* __restrict__ Ko,
    unsigned short* __restrict__ Vo) {
    const int b = blockIdx.x;
    const int g = b & 31;            // m-tile (XCD-pinned)
    const int r = b >> 5;            // 0..14 = (mode, n-tile)
    const int mode = r / 5;
    const int m0 = g * 128;
    const int n0 = (r % 5) * 128;
    const unsigned short* W = (mode == 0) ? wq : (mode == 1) ? wk : wv;
    unsigned short*       C = (mode == 0) ? Qo : (mode == 1) ? Ko : Vo;

    __shared__ unsigned short As[8192];   // 128 rows x 64
    __shared__ unsigned short Bs[8192];

    const int tid  = threadIdx.x;
    const int lane = tid & 63;
    const int wave = tid >> 6;
    const int quad = lane >> 4, l16 = lane & 15;
    const int wm = (wave >> 1) * 64, wn = (wave & 1) * 64;
    const int swz = l16 & 7;

    f32x4 acc[4][4] = {};

    int prow[4], pcol[4], lbase[4];
    for (int j = 0; j < 4; j++) {
        int p = j * 256 + tid;
        prow[j] = p >> 3;
        pcol[j] = ((p & 7) ^ (prow[j] & 7)) * 8;
        lbase[j] = (j * 256 + wave * 64) * 8;
    }

    for (int kt = 0; kt < D_MODEL; kt += 64) {
        __syncthreads();
        for (int j = 0; j < 4; j++) {
            stage16(&xb[(size_t)(m0 + prow[j]) * D_MODEL + kt + pcol[j]], As + lbase[j]);
            stage16(&W [(size_t)(n0 + prow[j]) * D_MODEL + kt + pcol[j]], Bs + lbase[j]);
        }
        __syncthreads();

        for (int s = 0; s < 2; s++) {
            bf16x8 af[4], bfr[4];
            for (int mi = 0; mi < 4; mi++) {
                int row = wm + mi * 16 + l16;
                af[mi] = *(const bf16x8*)&As[row * 64 + (((s << 2) + quad) ^ swz) * 8];
            }
            for (int ni = 0; ni < 4; ni++) {
                int row = wn + ni * 16 + l16;
                bfr[ni] = *(const bf16x8*)&Bs[row * 64 + (((s << 2) + quad) ^ swz) * 8];
            }
            for (int mi = 0; mi < 4; mi++)
                for (int ni = 0; ni < 4; ni++)
                    acc[mi][ni] = __builtin_amdgcn_mfma_f32_16x16x32_bf16(af[mi], bfr[ni], acc[mi][ni], 0, 0, 0);
        }
    }

    for (int mi = 0; mi < 4; mi++)
        for (int ni = 0; ni < 4; ni++) {
            u16x4 cv = cvt4(acc[mi][ni]);
            for (int r2 = 0; r2 < 4; r2++) {
                int row = m0 + wm + mi * 16 + quad * 4 + r2;
                int col = n0 + wn + ni * 16 + l16;
                C[(size_t)row * D_MODEL + col] = cv[r2];
            }
        }
}

// ------ fused per-head transpose -> fp8 (K',V') + Q->fp8 + vals zero -------
__global__ __launch_bounds__(256) void transpose_kv(
    const unsigned short* __restrict__ Kn, unsigned char* __restrict__ Kp8,
    const unsigned short* __restrict__ Vn, unsigned char* __restrict__ Vp8,
    const unsigned short* __restrict__ Qn, unsigned char* __restrict__ Qf8) {
    const int z = blockIdx.z;
    const int t = threadIdx.x;

    if (z >= 20) {   // Q convert: head slab, flat
        const size_t base = (size_t)(z - 20) * HSLAB + blockIdx.x * 4096 + t * 16;
        bf16x8 v0 = *(const bf16x8*)&Qn[base];
        bf16x8 v1 = *(const bf16x8*)&Qn[base + 8];
        f32x4 a = {(float)v0[0], (float)v0[1], (float)v0[2], (float)v0[3]};
        f32x4 b = {(float)v0[4], (float)v0[5], (float)v0[6], (float)v0[7]};
        f32x4 c = {(float)v1[0], (float)v1[1], (float)v1[2], (float)v1[3]};
        f32x4 d = {(float)v1[4], (float)v1[5], (float)v1[6], (float)v1[7]};
        u32x4 o = {pk_fp8(a), pk_fp8(b), pk_fp8(c), pk_fp8(d)};
        *(u32x4*)&Qf8[base] = o;
        return;
    }

    __shared__ unsigned short T[64][66];
    const unsigned short* src; unsigned char* dst;
    int R, Cc, r0, c0;
    if (z < 10) { src = Kn; dst = Kp8; R = 64;   Cc = 4096; r0 = 0; c0 = blockIdx.x * 64; }
    else        { src = Vn; dst = Vp8; R = 4096; Cc = 64;   r0 = blockIdx.x * 64; c0 = 0; }
    const size_t hb = (size_t)(z % 10) * HSLAB;
    const int rr = t >> 3, c8 = (t & 7) * 8;

    for (int hf = 0; hf < 2; hf++) {
        int r = rr + hf * 32;
        bf16x8 v = *(const bf16x8*)&src[hb + (size_t)(r0 + r) * Cc + c0 + c8];
        for (int j = 0; j < 8; j++) T[r][c8 + j] = ((unsigned short*)&v)[j];
    }
    __syncthreads();
    // zero the consumed source tile (Kn+Vn exactly cover the fp32 vals buf)
    const bf16x8 zz = {};
    for (int hf = 0; hf < 2; hf++) {
        int r = rr + hf * 32;
        *(bf16x8*)&((unsigned short*)src)[hb + (size_t)(r0 + r) * Cc + c0 + c8] = zz;
    }
    for (int hf = 0; hf < 2; hf++) {
        int oc = rr + hf * 32;
        f32x4 lo, hi;
        for (int j = 0; j < 4; j++) {
            lo[j] = __builtin_bit_cast(float, (unsigned int)T[c8 + j][oc] << 16);
            hi[j] = __builtin_bit_cast(float, (unsigned int)T[c8 + 4 + j][oc] << 16);
        }
        uint2 ov; ov.x = pk_fp8(lo); ov.y = pk_fp8(hi);
        size_t dcol = (z < 10) ? ((size_t)(c0 + oc) * 64 + r0 + c8)
                               : ((size_t)oc * 4096 + r0 + c8);
        *(uint2*)&dst[hb + dcol] = ov;
    }
}

// ------------------------------- attention (fp8) ---------------------------
// grid (320, 3): x = head*32 + qtile(128 rows), y = kpart (11/11/10 tiles of
// 128 keys). 4 waves x 32 q. R10-proven layouts; 2 barriers/tile:
//   top barrier -> stage K[t+1] (ping-pong) + V[t] -> S-phase (K[t], exp2,
//   P->LDS) -> mid barrier (drains vmcnt: V[t] ready, P visible) -> PV.
// LDS: K 2x8KB + V 8KB + P 16KB = 40KB -> exactly 4 blocks/CU.
__global__ __launch_bounds__(256, 4) void attn(
    const unsigned char* __restrict__ Qf8,   // [h][q][dk] fp8
    const unsigned char* __restrict__ Kp8,   // [h][key][dk] fp8
    const unsigned char* __restrict__ Vp8,   // [h][dk][key] fp8
    float* __restrict__ vals,                // pre-zeroed (transpose_kv)
    float* __restrict__ l_tot) {             // pre-zeroed (cvt_all)
    const int h  = blockIdx.x >> 5;
    const int qt = blockIdx.x & 31;
    const int ntile = (blockIdx.y == 2) ? 10 : 11;
    const int tile0 = blockIdx.y * 11;
    const int lane = threadIdx.x & 63;
    const int wave = threadIdx.x >> 6;
    const int quad = lane >> 4, l16 = lane & 15;
    const size_t hoff = (size_t)h * HSLAB;

    __shared__ unsigned char sm[40960];
    unsigned char* const Kb0 = sm;                      // 8KB, ping
    unsigned char* const Kb1 = sm + 8192;               // 8KB, pong
    unsigned char* const Vt  = sm + 16384;              // 8KB
    unsigned char* const Pw  = sm + 24576 + wave * 4096;// 4KB/wave

    const int qbase = qt * 128 + wave * 32;
    long qd[2][2];
    for (int g = 0; g < 2; g++) {
        const unsigned char* qp = Qf8 + hoff + (size_t)(qbase + g * 16 + l16) * 64 + quad * 8;
        qd[g][0] = *(const la64*)(qp);
        qd[g][1] = *(const la64*)(qp + 32);
    }

    f32x4 o[2][4] = {};
    f32x4 ol[2] = {};
    const long ONES8 = 0x3838383838383838L;   // e4m3 1.0 x8

    // staging: LDS chunk c holds: K (key=(c>>5)*8+(c&7), ci=(c>>3)&3)
    //                             V (dk =(c>>6)*8+(c&7), cv=(c>>3)&7)
    const int cA = wave * 64 + lane, cB = cA + 256;
    const int kKeyA = ((cA >> 5) << 3) + (cA & 7), kCiA = (cA >> 3) & 3;
    const int kKeyB = ((cB >> 5) << 3) + (cB & 7), kCiB = (cB >> 3) & 3;
    const int vDkA  = ((cA >> 6) << 3) + (cA & 7), vCvA = (cA >> 3) & 7;
    const int vDkB  = ((cB >> 6) << 3) + (cB & 7), vCvB = (cB >> 3) & 7;

    // fragment-read bases (R10-proven)
    const int kfb = (l16 >> 3) * 512 + (quad >> 1) * 128 + (l16 & 7) * 16 + (quad & 1) * 8;
    const int vfb = (l16 >> 3) * 1024 + (quad >> 1) * 128 + (l16 & 7) * 16 + (quad & 1) * 8;

    // prologue: stage K tile 0 into Kb0
    {
        const int keyb = tile0 << 7;
        stage16(Kp8 + hoff + (size_t)(keyb + kKeyA) * 64 + kCiA * 16, Kb0 + wave * 1024);
        stage16(Kp8 + hoff + (size_t)(keyb + kKeyB) * 64 + kCiB * 16, Kb0 + 4096 + wave * 1024);
    }

    for (int t = 0; t < ntile; t++) {
        const int keyb = (tile0 + t) << 7;
        unsigned char* const Kcur = (t & 1) ? Kb1 : Kb0;

        // K[t] drained by previous mid barrier (or here for t=0); Vt/Pw reads
        // of t-1 complete; K[t+1] buffer free.
        __syncthreads();

        if (t + 1 < ntile) {
            const int keyn = (tile0 + t + 1) << 7;
            unsigned char* const Knext = (t & 1) ? Kb0 : Kb1;
            stage16(Kp8 + hoff + (size_t)(keyn + kKeyA) * 64 + kCiA * 16, Knext + wave * 1024);
            stage16(Kp8 + hoff + (size_t)(keyn + kKeyB) * 64 + kCiB * 16, Knext + 4096 + wave * 1024);
        }
        stage16(Vp8 + hoff + (size_t)vDkA * N_TOK + keyb + vCvA * 16, Vt + wave * 1024);
        stage16(Vp8 + hoff + (size_t)vDkB * N_TOK + keyb + vCvB * 16, Vt + 4096 + wave * 1024);

        // ---- S^T: A = K rows (key), B = Q (pre-scaled); exp2 -> P fp8 ----
        for (int ni = 0; ni < 8; ni++) {
            const unsigned char* kp = Kcur + ni * 1024 + kfb;
            long a0 = *(const la64*)(kp);
            long a1 = *(const la64*)(kp + 256);
            for (int g = 0; g < 2; g++) {
                f32x4 s = {};
                s = __builtin_amdgcn_mfma_f32_16x16x32_fp8_fp8(a0, qd[g][0], s, 0, 0, 0);
                s = __builtin_amdgcn_mfma_f32_16x16x32_fp8_fp8(a1, qd[g][1], s, 0, 0, 0);
                f32x4 pv;
                for (int r = 0; r < 4; r++) pv[r] = EXP2(s[r]);
                *(ua32*)(Pw + (ni * 2 + (quad >> 1)) * 256 +
                         (g * 16 + l16) * 8 + (quad & 1) * 4) = pk_fp8(pv);
            }
        }

        // Drains vmcnt (V[t] + K[t+1] staged) and lgkmcnt (P visible).
        __syncthreads();

        // ---- O += P * V, l += P * 1 ----
        for (int ks = 0; ks < 4; ks++) {
            long vf[4];
            for (int nd = 0; nd < 4; nd++)
                vf[nd] = *(const la64*)(Vt + nd * 2048 + ks * 256 + vfb);
            for (int g = 0; g < 2; g++) {
                long pf = *(const la64*)(Pw + (ks * 4 + quad) * 256 + (g * 16 + l16) * 8);
                ol[g] = __builtin_amdgcn_mfma_f32_16x16x32_fp8_fp8(pf, ONES8, ol[g], 0, 0, 0);
                for (int nd = 0; nd < 4; nd++)
                    o[g][nd] = __builtin_amdgcn_mfma_f32_16x16x32_fp8_fp8(pf, vf[nd], o[g][nd], 0, 0, 0);
            }
        }
    }

    // l: C rows = q offset quad*4+r, cols identical -> write from l16==0
    if (l16 == 0)
        for (int g = 0; g < 2; g++)
            for (int r = 0; r < 4; r++)
                atomicAdd(&l_tot[(h << 12) + qbase + g * 16 + quad * 4 + r], ol[g][r]);

    for (int g = 0; g < 2; g++)
        for (int nd = 0; nd < 4; nd++)
            for (int r = 0; r < 4; r++) {
                int q = qbase + g * 16 + quad * 4 + r;
                atomicAdd(&vals[hoff + (size_t)q * DK + nd * 16 + l16], o[g][nd][r]);
            }
}

// ----------------- deferred normalize + residual + LayerNorm ---------------
__global__ __launch_bounds__(256) void ln_kernel(
    const float* __restrict__ vals, const float* __restrict__ l_tot,
    const float* __restrict__ x,
    const float* __restrict__ gamma, const float* __restrict__ beta,
    float* __restrict__ out) {
    const int wave = threadIdx.x >> 6, lane = threadIdx.x & 63;
    const int row  = blockIdx.x * 4 + wave;
    const float* v  = vals + (size_t)row * D_MODEL;
    const float* xr = x    + (size_t)row * D_MODEL;

    float t[10];
    float s = 0.f;
    for (int i = 0; i < 10; i++) {
        float linv = 1.0f / l_tot[row * 10 + i];
        t[i] = v[lane + i * 64] * linv + xr[lane + i * 64];
        s += t[i];
    }
    for (int off = 32; off; off >>= 1) s += __shfl_xor(s, off, 64);
    float mean = s * (1.0f / 640.0f);
    float s2 = 0.f;
    for (int i = 0; i < 10; i++) { float d = t[i] - mean; s2 += d * d; }
    for (int off = 32; off; off >>= 1) s2 += __shfl_xor(s2, off, 64);
    float inv = rsqrtf(s2 * (1.0f / 640.0f) + 1e-5f);

    float* orow = out + (size_t)row * D_MODEL;
    for (int i = 0; i < 10; i++) {
        int c = lane + i * 64;
        orow[c] = (t[i] - mean) * inv * gamma[c] + beta[c];
    }
}

// ------------------------------- launcher ----------------------------------
extern "C" void kernel_launch(void* const* d_in, const int* in_sizes, int n_in,
                              void* d_out, int out_size, void* d_ws, size_t ws_size,
                              hipStream_t stream) {
    const float* x     = (const float*)d_in[0];
    const float* Wq    = (const float*)d_in[1];
    const float* Wk    = (const float*)d_in[2];
    const float* Wv    = (const float*)d_in[3];
    const float* gamma = (const float*)d_in[4];
    const float* beta  = (const float*)d_in[5];
    float* out = (float*)d_out;

    char* ws = (char*)d_ws;
    unsigned short* xb  = (unsigned short*)(ws);               // 5,242,880 B
    unsigned char*  Qf8 = (unsigned char*)(ws);                // overlays xb (dead after gemm)
    unsigned short* wqb = (unsigned short*)(ws + 5242880);
    unsigned short* wkb = (unsigned short*)(ws + 6062080);
    unsigned short* wvb = (unsigned short*)(ws + 6881280);
    unsigned short* Qn  = (unsigned short*)(ws + 7700480);     // bf16 Q natural
    unsigned char*  Kp8 = (unsigned char*)(ws + 12943360);     // fp8 K' [h][key][dk]
    unsigned char*  Vp8 = (unsigned char*)(ws + 18186240);     // fp8 V' [h][dk][key]
    unsigned short* Kn  = (unsigned short*)(ws + 23429120);    // aliases vals
    unsigned short* Vn  = (unsigned short*)(ws + 28672000);    //  (exactly)
    float*          vals  = (float*)(ws + 23429120);           // 10,485,760 B
    float*          l_tot = (float*)(ws + 33914880);           //   163,840 B

    cvt_all<<<3800, 256, 0, stream>>>(x, Wq, Wk, Wv, xb, wqb, wkb, wvb,
                                      (f32x4*)l_tot);

    gemm_qkv<<<480, 256, 0, stream>>>(xb, wqb, wkb, wvb, Qn, Kn, Vn);

    transpose_kv<<<dim3(64, 1, 30), 256, 0, stream>>>(Kn, Kp8, Vn, Vp8, Qn, Qf8);

    attn<<<dim3(320, 3), 256, 0, stream>>>(Qf8, Kp8, Vp8, vals, l_tot);
    ln_kernel<<<1024, 256, 0, stream>>>(vals, l_tot, x, gamma, beta, out);
}